// Round 5
// baseline (1030.161 us; speedup 1.0000x reference)
//
#include <hip/hip_runtime.h>

typedef unsigned short u16;
typedef u16 u16x4 __attribute__((ext_vector_type(4)));
typedef u16 u16x8 __attribute__((ext_vector_type(8)));
typedef float f32x4 __attribute__((ext_vector_type(4)));
typedef __bf16 bf16x8 __attribute__((ext_vector_type(8)));

#define NN 16384
#define EE 262144
#define DD 1024
#define DESM 1280
#define LL 5000
#define IPN 30000

static __device__ __forceinline__ u16 f2bf(float f) {
  unsigned u = __float_as_uint(f);
  u += 0x7FFF + ((u >> 16) & 1);
  return (u16)(u >> 16);
}
static __device__ __forceinline__ float bf2f(u16 h) {
  return __uint_as_float(((unsigned)h) << 16);
}

// -------- generic fp32 -> bf16 cast, optional row gather, strided dst --------
__global__ void cast_rows_k(const float* __restrict__ src, int scols,
                            const int* __restrict__ rowidx,
                            u16* __restrict__ dst, int dld, int dcol0,
                            int rows, int cols8 /* cols/8 */) {
  long total = (long)rows * cols8;
  for (long i = blockIdx.x * (long)blockDim.x + threadIdx.x; i < total;
       i += (long)gridDim.x * blockDim.x) {
    int r = (int)(i / cols8);
    int k8 = (int)(i % cols8);
    int sr = rowidx ? rowidx[r] : r;
    const f32x4* s = (const f32x4*)(src + (size_t)sr * scols + (size_t)k8 * 8);
    f32x4 a = s[0], b = s[1];
    u16x8 o;
    o[0] = f2bf(a[0]); o[1] = f2bf(a[1]); o[2] = f2bf(a[2]); o[3] = f2bf(a[3]);
    o[4] = f2bf(b[0]); o[5] = f2bf(b[1]); o[6] = f2bf(b[2]); o[7] = f2bf(b[3]);
    *(u16x8*)(dst + (size_t)r * dld + dcol0 + (size_t)k8 * 8) = o;
  }
}

// -------- EmbeddingBag(sum) over bf16 table + bias2 (pre-relu), fp32 out --------
__global__ void embed_bag_k(const u16* __restrict__ W, const int* __restrict__ idx,
                            const int* __restrict__ off, const float* __restrict__ bias2,
                            float* __restrict__ x2pre) {
  int n = blockIdx.x;
  int t = threadIdx.x;  // 256 threads, 4 cols each
  int beg = off[n], end = off[n + 1];
  f32x4 acc = {0.f, 0.f, 0.f, 0.f};
  for (int p = beg; p < end; ++p) {
    int row = idx[p];
    u16x4 v = *(const u16x4*)(W + (size_t)row * DD + t * 4);
    acc[0] += bf2f(v[0]); acc[1] += bf2f(v[1]);
    acc[2] += bf2f(v[2]); acc[3] += bf2f(v[3]);
  }
  acc += *(const f32x4*)(bias2 + t * 4);
  *(f32x4*)(x2pre + (size_t)n * DD + t * 4) = acc;
}

// -------- CSR build over dst --------
__global__ void hist_k(const int* __restrict__ dst, int* __restrict__ counts) {
  int e = blockIdx.x * blockDim.x + threadIdx.x;
  if (e < EE) atomicAdd(&counts[dst[e]], 1);
}

__global__ void scan_k(const int* __restrict__ counts, int* __restrict__ row_off) {
  __shared__ int sh[256];
  int t = threadIdx.x;  // 256 threads, 64 elems each
  int s = 0;
  for (int i = 0; i < 64; ++i) s += counts[t * 64 + i];
  sh[t] = s;
  __syncthreads();
  if (t == 0) {
    int run = 0;
    for (int i = 0; i < 256; ++i) { int v = sh[i]; sh[i] = run; run += v; }
    row_off[NN] = run;
  }
  __syncthreads();
  int run = sh[t];
  for (int i = 0; i < 64; ++i) { row_off[t * 64 + i] = run; run += counts[t * 64 + i]; }
}

__global__ void scatter_k(const int* __restrict__ dst, int* __restrict__ cursor,
                          int* __restrict__ perm) {
  int e = blockIdx.x * blockDim.x + threadIdx.x;
  if (e < EE) {
    int pos = atomicAdd(&cursor[dst[e]], 1);
    perm[pos] = e;
  }
}

// -------- per-node gather aggregation: cat = [ppi_out | res] in bf16 --------
__global__ void aggregate_k(const u16* __restrict__ h, const int* __restrict__ row_off,
                            const int* __restrict__ perm, const float* __restrict__ self_w,
                            const float* __restrict__ ppi_w, const int* __restrict__ src,
                            u16* __restrict__ cat) {
  int n = blockIdx.x;
  int t = threadIdx.x;  // 256 threads, 4 cols each
  int beg = row_off[n], end = row_off[n + 1];
  f32x4 res = {0.f, 0.f, 0.f, 0.f}, ppi = {0.f, 0.f, 0.f, 0.f};
  for (int p = beg; p < end; ++p) {
    int e = perm[p];
    int s = src[e];
    float ws = self_w[e], wp = ppi_w[e];
    u16x4 m = *(const u16x4*)(h + (size_t)s * DD + t * 4);
    f32x4 mf = {bf2f(m[0]), bf2f(m[1]), bf2f(m[2]), bf2f(m[3])};
    res += ws * mf;
    ppi += wp * mf;
  }
  u16x4 o0, o1;
  o0[0] = f2bf(ppi[0]); o0[1] = f2bf(ppi[1]); o0[2] = f2bf(ppi[2]); o0[3] = f2bf(ppi[3]);
  o1[0] = f2bf(res[0]); o1[1] = f2bf(res[1]); o1[2] = f2bf(res[2]); o1[3] = f2bf(res[3]);
  *(u16x4*)(cat + (size_t)n * 2048 + t * 4) = o0;
  *(u16x4*)(cat + (size_t)n * 2048 + DD + t * 4) = o1;
}

// ======== 256x256x64 8-wave fully-pipelined GEMM (T1+T2+T3+T4+T5) ========
// C = A[M,K] @ B[N,K]^T.  LDS per matrix: [dbuf][khalf][256 rows][32 cols bf16];
// read swizzle slot^=(row>>1)&3, staged via pre-swizzled global source (verified
// conflict-free, round 3).  FULL register pipeline: A (afP/afQ) and B (bqP/bqQ)
// fragments are each read one phase before their consuming MFMA cluster, across a
// barrier — no MFMA ever waits on a same-phase ds_read (round-4's residual stall).
//   reads:  P1:{A-mhi-kk0(t), B-kk1(t)}  P2:{A-mhi-kk1(t)}  P3:{A-mlo-kk1(t)}
//           P4:{A-mlo-kk0(t+1), B-kk0(t+1)}
//   MFMA:   P1: mlo*kk0 (afP,bqP)   P2: mhi*kk0 (afQ,bqP)
//           P3: mhi*kk1 (afP,bqQ)   P4: mlo*kk1 (afQ,bqQ)
//   stages: P1:A1(t+1)  P2:B0(t+2)  P3:A0(t+2)  P4:B1(t+2)
// vmcnt ledger (audited): vmcnt(8) @P1-end guarantees A1(t) before P2's read;
// vmcnt(6) @P3-end guarantees B1(t+1)/A0(t+1)/B0(t+1) before P4/(t+1).P1 reads.
// (vmcnt-then-barrier makes per-wave vmcnt a cross-wave guarantee.)  In-flight
// never drops below 3 half-tiles.
static __device__ __forceinline__ void stage_half(const char* Gb, size_t ldb, int rowbase,
                                                  int rowmax, int kbyte, char* lds_half_w,
                                                  int s_rowoff, int s_inner) {
#pragma unroll
  for (int j = 0; j < 2; ++j) {
    int row = rowbase + j * 128 + s_rowoff;
    if (row > rowmax) row = rowmax;
    const char* src = Gb + (size_t)row * ldb + kbyte + s_inner;
    __builtin_amdgcn_global_load_lds(
        (const __attribute__((address_space(1))) void*)src,
        (__attribute__((address_space(3))) void*)(lds_half_w + j * 8192), 16, 0, 0);
  }
}

static __device__ __forceinline__ bf16x8 ldr(const char* kh, int row, int slot) {
  unsigned a = (unsigned)row * 64u +
               ((((unsigned)slot << 4) ^ ((((unsigned)row >> 1) & 3u) << 4)));
  return *(const bf16x8*)(kh + a);
}

// MODE 0: h = bf16(sm0*relu(acc+bias0+bias1) + sm1*relu(x2pre))   (bf16 out)
// MODE 1: bf16(relu(acc + bias0))                                  (bf16 out)
// MODE 2: acc + bias0, fp32 out, col-guard vs N
template <int MODE>
__global__ __launch_bounds__(512, 2) void gemm8_k(
    const u16* __restrict__ A, const u16* __restrict__ B, int M, int N, int K,
    void* __restrict__ Cout, int ldc, const float* __restrict__ bias0,
    const float* __restrict__ bias1, const float* __restrict__ x2pre,
    const float* __restrict__ wmix) {
  __shared__ char lds[131072];
  char* ldsA = lds;            // [2][2][16384]
  char* ldsB = lds + 65536;    // [2][2][16384]
  const int tid = threadIdx.x;
  const int lane = tid & 63;
  const int wid = tid >> 6;
  const int wr = wid >> 2;   // 2 M-waves (128 rows each)
  const int wc = wid & 3;    // 4 N-waves (64 cols each)
  // bijective XCD chunk swizzle (grids are multiples of 8)
  const int nwg = gridDim.x * gridDim.y;
  const int flat = blockIdx.x + gridDim.x * blockIdx.y;
  const int swz = (flat & 7) * (nwg >> 3) + (flat >> 3);
  const int row0 = (swz / gridDim.x) * 256;
  const int col0 = (swz % gridDim.x) * 256;
  const int NT = K >> 6;
  const size_t lda = (size_t)K * 2;
  const char* Ab = (const char*)A;
  const char* Bb = (const char*)B;
  const int l15 = lane & 15;
  const int slot = lane >> 4;
  const int s_rowoff = wid * 16 + (lane >> 2);
  const int s_inner = (((lane & 3) << 4) ^ (((lane >> 3) & 3) << 4));
  const int wb = wid * 1024;

  f32x4 acc[8][4];
#pragma unroll
  for (int m = 0; m < 8; ++m)
#pragma unroll
    for (int n = 0; n < 4; ++n) acc[m][n] = (f32x4){0.f, 0.f, 0.f, 0.f};

  // prologue stages (7 halves): B0(0),A0(0),A1(0),B1(0) | B0(1),A0(1),B1(1)
  const int k1 = (NT > 1) ? 128 : 0;
  stage_half(Bb, lda, col0, N - 1, 0,       ldsB + 0     + wb, s_rowoff, s_inner);
  stage_half(Ab, lda, row0, M - 1, 0,       ldsA + 0     + wb, s_rowoff, s_inner);
  stage_half(Ab, lda, row0, M - 1, 64,      ldsA + 16384 + wb, s_rowoff, s_inner);
  stage_half(Bb, lda, col0, N - 1, 64,      ldsB + 16384 + wb, s_rowoff, s_inner);
  stage_half(Bb, lda, col0, N - 1, k1,      ldsB + 32768 + wb, s_rowoff, s_inner);
  stage_half(Ab, lda, row0, M - 1, k1,      ldsA + 32768 + wb, s_rowoff, s_inner);
  stage_half(Bb, lda, col0, N - 1, k1 + 64, ldsB + 49152 + wb, s_rowoff, s_inner);
  asm volatile("s_waitcnt vmcnt(6)" ::: "memory");  // tile-0 (all 4 halves) landed
  __builtin_amdgcn_s_barrier();

  bf16x8 afP[4], afQ[4], bqP[4], bqQ[4];
  // pre-loop reads (the "P4 of t=-1"): afP=A-mlo-kk0(0), bqP=B-kk0(0)
#pragma unroll
  for (int m = 0; m < 4; ++m) afP[m] = ldr(ldsA, wr * 128 + m * 16 + l15, slot);
#pragma unroll
  for (int n = 0; n < 4; ++n) bqP[n] = ldr(ldsB, wc * 64 + n * 16 + l15, slot);

  for (int t = 0; t < NT; ++t) {
    const int d = t & 1;
    char* Ad = ldsA + d * 32768;
    char* Bd = ldsB + d * 32768;
    const char* Akh1 = Ad + 16384;
    const char* Bkh1 = Bd + 16384;
    const char* AkhN0 = ldsA + (d ^ 1) * 32768;  // next-tile A kh0
    const char* BkhN0 = ldsB + (d ^ 1) * 32768;  // next-tile B kh0
    const int ts1 = (t + 1 < NT) ? t + 1 : NT - 1;
    const int ts2 = (t + 2 < NT) ? t + 2 : NT - 1;

    // ---- P1: read afQ=A-mhi-kk0(t), bqQ=B-kk1(t); stage A1(t+1); MFMA mlo*kk0
#pragma unroll
    for (int m = 0; m < 4; ++m) afQ[m] = ldr(Ad, wr * 128 + (m + 4) * 16 + l15, slot);
#pragma unroll
    for (int n = 0; n < 4; ++n) bqQ[n] = ldr(Bkh1, wc * 64 + n * 16 + l15, slot);
    stage_half(Ab, lda, row0, M - 1, ts1 * 128 + 64,
               ldsA + ((t + 1) & 1) * 32768 + 16384 + wb, s_rowoff, s_inner);
    __builtin_amdgcn_sched_barrier(0);
    __builtin_amdgcn_s_setprio(1);
#pragma unroll
    for (int m = 0; m < 4; ++m)
#pragma unroll
      for (int n = 0; n < 4; ++n)
        acc[m][n] = __builtin_amdgcn_mfma_f32_16x16x32_bf16(afP[m], bqP[n], acc[m][n], 0, 0, 0);
    __builtin_amdgcn_s_setprio(0);
    asm volatile("s_waitcnt vmcnt(8)" ::: "memory");
    __builtin_amdgcn_s_barrier();

    // ---- P2: read afP=A-mhi-kk1(t); stage B0(t+2); MFMA mhi*kk0
#pragma unroll
    for (int m = 0; m < 4; ++m) afP[m] = ldr(Akh1, wr * 128 + (m + 4) * 16 + l15, slot);
    stage_half(Bb, lda, col0, N - 1, ts2 * 128, Bd + wb, s_rowoff, s_inner);
    __builtin_amdgcn_sched_barrier(0);
    __builtin_amdgcn_s_setprio(1);
#pragma unroll
    for (int m = 0; m < 4; ++m)
#pragma unroll
      for (int n = 0; n < 4; ++n)
        acc[m + 4][n] = __builtin_amdgcn_mfma_f32_16x16x32_bf16(afQ[m], bqP[n], acc[m + 4][n], 0, 0, 0);
    __builtin_amdgcn_s_setprio(0);
    __builtin_amdgcn_s_barrier();

    // ---- P3: read afQ=A-mlo-kk1(t); stage A0(t+2); MFMA mhi*kk1
#pragma unroll
    for (int m = 0; m < 4; ++m) afQ[m] = ldr(Akh1, wr * 128 + m * 16 + l15, slot);
    stage_half(Ab, lda, row0, M - 1, ts2 * 128, Ad + wb, s_rowoff, s_inner);
    __builtin_amdgcn_sched_barrier(0);
    __builtin_amdgcn_s_setprio(1);
#pragma unroll
    for (int m = 0; m < 4; ++m)
#pragma unroll
      for (int n = 0; n < 4; ++n)
        acc[m + 4][n] = __builtin_amdgcn_mfma_f32_16x16x32_bf16(afP[m], bqQ[n], acc[m + 4][n], 0, 0, 0);
    __builtin_amdgcn_s_setprio(0);
    asm volatile("s_waitcnt vmcnt(6)" ::: "memory");
    __builtin_amdgcn_s_barrier();

    // ---- P4: read afP=A-mlo-kk0(t+1), bqP=B-kk0(t+1); stage B1(t+2); MFMA mlo*kk1
#pragma unroll
    for (int m = 0; m < 4; ++m) afP[m] = ldr(AkhN0, wr * 128 + m * 16 + l15, slot);
#pragma unroll
    for (int n = 0; n < 4; ++n) bqP[n] = ldr(BkhN0, wc * 64 + n * 16 + l15, slot);
    stage_half(Bb, lda, col0, N - 1, ts2 * 128 + 64, Bd + 16384 + wb, s_rowoff, s_inner);
    __builtin_amdgcn_sched_barrier(0);
    __builtin_amdgcn_s_setprio(1);
#pragma unroll
    for (int m = 0; m < 4; ++m)
#pragma unroll
      for (int n = 0; n < 4; ++n)
        acc[m][n] = __builtin_amdgcn_mfma_f32_16x16x32_bf16(afQ[m], bqQ[n], acc[m][n], 0, 0, 0);
    __builtin_amdgcn_s_setprio(0);
    __builtin_amdgcn_s_barrier();
  }

  float sm0 = 0.f, sm1 = 0.f;
  if (MODE == 0) {
    float w0 = wmix[0], w1 = wmix[1];
    float mx = fmaxf(w0, w1);
    float e0 = expf(w0 - mx), e1 = expf(w1 - mx);
    float inv = 1.f / (e0 + e1);
    sm0 = e0 * inv;
    sm1 = e1 * inv;
  }
  float bc[4];
  int cs[4];
#pragma unroll
  for (int n = 0; n < 4; ++n) {
    int c = col0 + wc * 64 + n * 16 + l15;
    cs[n] = c;
    bc[n] = (MODE == 2 && c >= N) ? 0.f : (bias0[c] + (MODE == 0 ? bias1[c] : 0.f));
  }
#pragma unroll
  for (int m = 0; m < 8; ++m) {
#pragma unroll
    for (int n = 0; n < 4; ++n) {
      int c = cs[n];
      if (MODE == 2 && c >= N) continue;
      int r0 = row0 + wr * 128 + m * 16 + slot * 4;
#pragma unroll
      for (int r = 0; r < 4; ++r) {
        float v = acc[m][n][r] + bc[n];
        int rr = r0 + r;
        if (MODE == 0) {
          float x1v = fmaxf(v, 0.f);
          float x2v = fmaxf(x2pre[(size_t)rr * DD + c], 0.f);
          ((u16*)Cout)[(size_t)rr * ldc + c] = f2bf(sm0 * x1v + sm1 * x2v);
        } else if (MODE == 1) {
          ((u16*)Cout)[(size_t)rr * ldc + c] = f2bf(fmaxf(v, 0.f));
        } else {
          ((float*)Cout)[(size_t)rr * ldc + c] = v;
        }
      }
    }
  }
}

extern "C" void kernel_launch(void* const* d_in, const int* in_sizes, int n_in,
                              void* d_out, int out_size, void* d_ws, size_t ws_size,
                              hipStream_t stream) {
  const float* esm   = (const float*)d_in[0];
  const float* ipw   = (const float*)d_in[1];
  const float* Wesm  = (const float*)d_in[2];
  const float* besm  = (const float*)d_in[3];
  const float* bias1 = (const float*)d_in[4];
  const float* bias2 = (const float*)d_in[5];
  const float* wmix  = (const float*)d_in[6];
  const float* Wupd  = (const float*)d_in[7];
  const float* bupd  = (const float*)d_in[8];
  const float* Wout  = (const float*)d_in[9];
  const float* bout  = (const float*)d_in[10];
  const float* selfw = (const float*)d_in[11];
  const float* ppiw  = (const float*)d_in[12];
  const int* inputs  = (const int*)d_in[13];
  const int* ipidx   = (const int*)d_in[14];
  const int* ipoff   = (const int*)d_in[15];
  const int* src     = (const int*)d_in[16];
  const int* dst     = (const int*)d_in[17];
  const int* tgt     = (const int*)d_in[18];
  float* out = (float*)d_out;

  char* ws = (char*)d_ws;
  size_t o = 0;
  auto take = [&](size_t b) {
    char* r = ws + o;
    o += (b + 255) & ~(size_t)255;
    return r;
  };
  u16* Wesm_b = (u16*)take(1024ull * 1280 * 2);
  u16* Wupd_b = (u16*)take(2ull * 1024 * 2048 * 2);
  u16* Wout_b = (u16*)take(5000ull * 2304 * 2);
  int* counts  = (int*)take((size_t)NN * 4);
  int* row_off = (int*)take((size_t)(NN + 1) * 4);
  int* cursor  = (int*)take((size_t)NN * 4);
  int* perm    = (int*)take((size_t)EE * 4);
  u16* h_b     = (u16*)take((size_t)NN * DD * 2);
  // overlapping region (disjoint lifetimes):
  //   phase A: x2pre [N,1024]f32 @0 ; A1 [N,1280]bf16 ; ipw_b [30000,1024]bf16
  //   phase B: cat [N,2048]bf16 @0  ; A_last [N,2304]bf16
  char* shared0 = ws + o;
  size_t x2_b = ((size_t)NN * DD * 4 + 255) & ~(size_t)255;
  size_t a1_b = ((size_t)NN * DESM * 2 + 255) & ~(size_t)255;
  float* x2pre = (float*)shared0;
  u16* A1     = (u16*)(shared0 + x2_b);
  u16* ipw_b  = (u16*)(shared0 + x2_b + a1_b);
  u16* cat_b  = (u16*)shared0;
  u16* A_last = (u16*)(shared0 + x2_b);

  // ---- weight casts to bf16 ----
  cast_rows_k<<<2048, 256, 0, stream>>>(Wesm, 1280, nullptr, Wesm_b, 1280, 0, 1024, 160);
  cast_rows_k<<<2048, 256, 0, stream>>>(Wupd, 2048, nullptr, Wupd_b, 2048, 0, 2048, 256);
  cast_rows_k<<<2048, 256, 0, stream>>>(Wout, 2304, nullptr, Wout_b, 2304, 0, 5000, 288);
  cast_rows_k<<<4096, 256, 0, stream>>>(ipw, 1024, nullptr, ipw_b, 1024, 0, IPN, 128);

  // ---- x2 pre-activation (embedding bag over bf16 table + bias2) ----
  embed_bag_k<<<NN, 256, 0, stream>>>(ipw_b, ipidx, ipoff, bias2, x2pre);

  // ---- gather ESM rows for x1 GEMM ----
  cast_rows_k<<<4096, 256, 0, stream>>>(esm, 1280, inputs, A1, 1280, 0, NN, 160);

  // ---- CSR by dst (shared by both GCN layers) ----
  hipMemsetAsync(counts, 0, (size_t)NN * 4, stream);
  hist_k<<<EE / 256, 256, 0, stream>>>(dst, counts);
  scan_k<<<1, 256, 0, stream>>>(counts, row_off);
  hipMemcpyAsync(cursor, row_off, (size_t)NN * 4, hipMemcpyDeviceToDevice, stream);
  scatter_k<<<EE / 256, 256, 0, stream>>>(dst, cursor, perm);

  // ---- x1 GEMM fused with softmax-mix of x2 -> h (bf16) ----
  gemm8_k<0><<<dim3(4, 64), 512, 0, stream>>>(A1, Wesm_b, NN, 1024, 1280, h_b, 1024,
                                              besm, bias1, x2pre, wmix);

  // ---- ESM gather for the final concat (A1/ipw_b dead now) ----
  cast_rows_k<<<4096, 256, 0, stream>>>(esm, 1280, tgt, A_last, 2304, 1024, NN, 160);

  // ---- GCN layer 0 ----
  aggregate_k<<<NN, 256, 0, stream>>>(h_b, row_off, perm, selfw, ppiw, src, cat_b);
  gemm8_k<1><<<dim3(4, 64), 512, 0, stream>>>(cat_b, Wupd_b, NN, 1024, 2048, h_b, 1024,
                                              bupd, nullptr, nullptr, nullptr);

  // ---- GCN layer 1 (writes h directly into A_last[:, :1024]) ----
  aggregate_k<<<NN, 256, 0, stream>>>(h_b, row_off, perm, selfw, ppiw, src, cat_b);
  gemm8_k<1><<<dim3(4, 64), 512, 0, stream>>>(cat_b, Wupd_b + (size_t)1024 * 2048, NN, 1024,
                                              2048, A_last, 2304, bupd + 1024, nullptr,
                                              nullptr, nullptr);

  // ---- final output GEMM [16384,2304] x [5000,2304]^T ----
  gemm8_k<2><<<dim3(20, 64), 512, 0, stream>>>(A_last, Wout_b, NN, 5000, 2304, out, 5000,
                                               bout, nullptr, nullptr, nullptr);
}

// Round 6
// 930.409 us; speedup vs baseline: 1.1072x; 1.1072x over previous
//
#include <hip/hip_runtime.h>

typedef unsigned short u16;
typedef u16 u16x4 __attribute__((ext_vector_type(4)));
typedef u16 u16x8 __attribute__((ext_vector_type(8)));
typedef float f32x4 __attribute__((ext_vector_type(4)));
typedef __bf16 bf16x8 __attribute__((ext_vector_type(8)));

#define NN 16384
#define EE 262144
#define DD 1024
#define DESM 1280
#define LL 5000
#define IPN 30000

static __device__ __forceinline__ u16 f2bf(float f) {
  unsigned u = __float_as_uint(f);
  u += 0x7FFF + ((u >> 16) & 1);
  return (u16)(u >> 16);
}
static __device__ __forceinline__ float bf2f(u16 h) {
  return __uint_as_float(((unsigned)h) << 16);
}

// -------- generic fp32 -> bf16 cast, optional row gather, strided dst --------
__global__ void cast_rows_k(const float* __restrict__ src, int scols,
                            const int* __restrict__ rowidx,
                            u16* __restrict__ dst, int dld, int dcol0,
                            int rows, int cols8 /* cols/8 */) {
  long total = (long)rows * cols8;
  for (long i = blockIdx.x * (long)blockDim.x + threadIdx.x; i < total;
       i += (long)gridDim.x * blockDim.x) {
    int r = (int)(i / cols8);
    int k8 = (int)(i % cols8);
    int sr = rowidx ? rowidx[r] : r;
    const f32x4* s = (const f32x4*)(src + (size_t)sr * scols + (size_t)k8 * 8);
    f32x4 a = s[0], b = s[1];
    u16x8 o;
    o[0] = f2bf(a[0]); o[1] = f2bf(a[1]); o[2] = f2bf(a[2]); o[3] = f2bf(a[3]);
    o[4] = f2bf(b[0]); o[5] = f2bf(b[1]); o[6] = f2bf(b[2]); o[7] = f2bf(b[3]);
    *(u16x8*)(dst + (size_t)r * dld + dcol0 + (size_t)k8 * 8) = o;
  }
}

// -------- EmbeddingBag(sum) over bf16 table + bias2, relu, bf16 out --------
// 2 nodes / 256-thread block; 8 cols/thread (u16x8); 8-deep gather pipeline so
// 8 row-loads are in flight per wave (previous version was 1-deep = latency-bound).
__global__ void embed_bag_k(const u16* __restrict__ W, const int* __restrict__ idx,
                            const int* __restrict__ off, const float* __restrict__ bias2,
                            u16* __restrict__ x2b) {
  int node = blockIdx.x * 2 + (threadIdx.x >> 7);
  int t = threadIdx.x & 127;
  int beg = off[node], end = off[node + 1];
  float a[8];
#pragma unroll
  for (int j = 0; j < 8; ++j) a[j] = 0.f;
  int p = beg;
  for (; p + 8 <= end; p += 8) {
    u16x8 v[8];
#pragma unroll
    for (int q = 0; q < 8; ++q)
      v[q] = *(const u16x8*)(W + (size_t)idx[p + q] * DD + t * 8);
#pragma unroll
    for (int q = 0; q < 8; ++q)
#pragma unroll
      for (int j = 0; j < 8; ++j) a[j] += bf2f(v[q][j]);
  }
  for (; p + 2 <= end; p += 2) {
    u16x8 v0 = *(const u16x8*)(W + (size_t)idx[p] * DD + t * 8);
    u16x8 v1 = *(const u16x8*)(W + (size_t)idx[p + 1] * DD + t * 8);
#pragma unroll
    for (int j = 0; j < 8; ++j) a[j] += bf2f(v0[j]) + bf2f(v1[j]);
  }
  if (p < end) {
    u16x8 v0 = *(const u16x8*)(W + (size_t)idx[p] * DD + t * 8);
#pragma unroll
    for (int j = 0; j < 8; ++j) a[j] += bf2f(v0[j]);
  }
  f32x4 b0 = *(const f32x4*)(bias2 + t * 8);
  f32x4 b1 = *(const f32x4*)(bias2 + t * 8 + 4);
  u16x8 o;
#pragma unroll
  for (int j = 0; j < 4; ++j) o[j] = f2bf(fmaxf(a[j] + b0[j], 0.f));
#pragma unroll
  for (int j = 0; j < 4; ++j) o[j + 4] = f2bf(fmaxf(a[j + 4] + b1[j], 0.f));
  *(u16x8*)(x2b + (size_t)node * DD + t * 8) = o;
}

// -------- CSR build over dst --------
__global__ void hist_k(const int* __restrict__ dst, int* __restrict__ counts) {
  int e = blockIdx.x * blockDim.x + threadIdx.x;
  if (e < EE) atomicAdd(&counts[dst[e]], 1);
}

__global__ void scan_k(const int* __restrict__ counts, int* __restrict__ row_off) {
  __shared__ int sh[256];
  int t = threadIdx.x;  // 256 threads, 64 elems each
  int s = 0;
  for (int i = 0; i < 64; ++i) s += counts[t * 64 + i];
  sh[t] = s;
  __syncthreads();
  if (t == 0) {
    int run = 0;
    for (int i = 0; i < 256; ++i) { int v = sh[i]; sh[i] = run; run += v; }
    row_off[NN] = run;
  }
  __syncthreads();
  int run = sh[t];
  for (int i = 0; i < 64; ++i) { row_off[t * 64 + i] = run; run += counts[t * 64 + i]; }
}

// scatter edges into packed 16B records ordered by dst-CSR position:
// rec = {src, self_w(bits), ppi_w(bits), 0} — one load per edge at aggregate time.
__global__ void scatter_k(const int* __restrict__ dst, const int* __restrict__ src,
                          const float* __restrict__ selfw, const float* __restrict__ ppiw,
                          int* __restrict__ cursor, int4* __restrict__ rec) {
  int e = blockIdx.x * blockDim.x + threadIdx.x;
  if (e < EE) {
    int pos = atomicAdd(&cursor[dst[e]], 1);
    int4 r;
    r.x = src[e];
    r.y = __float_as_int(selfw[e]);
    r.z = __float_as_int(ppiw[e]);
    r.w = 0;
    rec[pos] = r;
  }
}

// -------- per-node gather aggregation: cat = [ppi_out | res] in bf16 --------
// 2 nodes / 256-thread block; 8 cols/thread; 4-deep gather pipeline.
__global__ void aggregate_k(const u16* __restrict__ h, const int* __restrict__ row_off,
                            const int4* __restrict__ rec, u16* __restrict__ cat) {
  int node = blockIdx.x * 2 + (threadIdx.x >> 7);
  int t = threadIdx.x & 127;
  int beg = row_off[node], end = row_off[node + 1];
  float res[8], ppi[8];
#pragma unroll
  for (int j = 0; j < 8; ++j) { res[j] = 0.f; ppi[j] = 0.f; }
  int p = beg;
  for (; p + 4 <= end; p += 4) {
    int4 r[4];
    u16x8 m[4];
#pragma unroll
    for (int q = 0; q < 4; ++q) r[q] = rec[p + q];
#pragma unroll
    for (int q = 0; q < 4; ++q)
      m[q] = *(const u16x8*)(h + (size_t)r[q].x * DD + t * 8);
#pragma unroll
    for (int q = 0; q < 4; ++q) {
      float ws = __int_as_float(r[q].y), wp = __int_as_float(r[q].z);
#pragma unroll
      for (int j = 0; j < 8; ++j) {
        float f = bf2f(m[q][j]);
        res[j] += ws * f;
        ppi[j] += wp * f;
      }
    }
  }
  for (; p < end; ++p) {
    int4 r0 = rec[p];
    u16x8 m0 = *(const u16x8*)(h + (size_t)r0.x * DD + t * 8);
    float ws = __int_as_float(r0.y), wp = __int_as_float(r0.z);
#pragma unroll
    for (int j = 0; j < 8; ++j) {
      float f = bf2f(m0[j]);
      res[j] += ws * f;
      ppi[j] += wp * f;
    }
  }
  u16x8 o0, o1;
#pragma unroll
  for (int j = 0; j < 8; ++j) { o0[j] = f2bf(ppi[j]); o1[j] = f2bf(res[j]); }
  *(u16x8*)(cat + (size_t)node * 2048 + t * 8) = o0;
  *(u16x8*)(cat + (size_t)node * 2048 + DD + t * 8) = o1;
}

// ======== 256x256x64 8-wave fully-pipelined GEMM (T1+T2+T3+T4+T5) ========
// (unchanged from round 5 — see that round's ledger comments)
static __device__ __forceinline__ void stage_half(const char* Gb, size_t ldb, int rowbase,
                                                  int rowmax, int kbyte, char* lds_half_w,
                                                  int s_rowoff, int s_inner) {
#pragma unroll
  for (int j = 0; j < 2; ++j) {
    int row = rowbase + j * 128 + s_rowoff;
    if (row > rowmax) row = rowmax;
    const char* src = Gb + (size_t)row * ldb + kbyte + s_inner;
    __builtin_amdgcn_global_load_lds(
        (const __attribute__((address_space(1))) void*)src,
        (__attribute__((address_space(3))) void*)(lds_half_w + j * 8192), 16, 0, 0);
  }
}

static __device__ __forceinline__ bf16x8 ldr(const char* kh, int row, int slot) {
  unsigned a = (unsigned)row * 64u +
               ((((unsigned)slot << 4) ^ ((((unsigned)row >> 1) & 3u) << 4)));
  return *(const bf16x8*)(kh + a);
}

// MODE 0: h = bf16(sm0*relu(acc+bias0+bias1) + sm1*x2b)  (x2b pre-relu'd bf16)
// MODE 1: bf16(relu(acc + bias0))
// MODE 2: acc + bias0, fp32 out, col-guard vs N
template <int MODE>
__global__ __launch_bounds__(512, 2) void gemm8_k(
    const u16* __restrict__ A, const u16* __restrict__ B, int M, int N, int K,
    void* __restrict__ Cout, int ldc, const float* __restrict__ bias0,
    const float* __restrict__ bias1, const u16* __restrict__ x2b,
    const float* __restrict__ wmix) {
  __shared__ char lds[131072];
  char* ldsA = lds;            // [2][2][16384]
  char* ldsB = lds + 65536;    // [2][2][16384]
  const int tid = threadIdx.x;
  const int lane = tid & 63;
  const int wid = tid >> 6;
  const int wr = wid >> 2;
  const int wc = wid & 3;
  const int nwg = gridDim.x * gridDim.y;
  const int flat = blockIdx.x + gridDim.x * blockIdx.y;
  const int swz = (flat & 7) * (nwg >> 3) + (flat >> 3);
  const int row0 = (swz / gridDim.x) * 256;
  const int col0 = (swz % gridDim.x) * 256;
  const int NT = K >> 6;
  const size_t lda = (size_t)K * 2;
  const char* Ab = (const char*)A;
  const char* Bb = (const char*)B;
  const int l15 = lane & 15;
  const int slot = lane >> 4;
  const int s_rowoff = wid * 16 + (lane >> 2);
  const int s_inner = (((lane & 3) << 4) ^ (((lane >> 3) & 3) << 4));
  const int wb = wid * 1024;

  f32x4 acc[8][4];
#pragma unroll
  for (int m = 0; m < 8; ++m)
#pragma unroll
    for (int n = 0; n < 4; ++n) acc[m][n] = (f32x4){0.f, 0.f, 0.f, 0.f};

  const int k1 = (NT > 1) ? 128 : 0;
  stage_half(Bb, lda, col0, N - 1, 0,       ldsB + 0     + wb, s_rowoff, s_inner);
  stage_half(Ab, lda, row0, M - 1, 0,       ldsA + 0     + wb, s_rowoff, s_inner);
  stage_half(Ab, lda, row0, M - 1, 64,      ldsA + 16384 + wb, s_rowoff, s_inner);
  stage_half(Bb, lda, col0, N - 1, 64,      ldsB + 16384 + wb, s_rowoff, s_inner);
  stage_half(Bb, lda, col0, N - 1, k1,      ldsB + 32768 + wb, s_rowoff, s_inner);
  stage_half(Ab, lda, row0, M - 1, k1,      ldsA + 32768 + wb, s_rowoff, s_inner);
  stage_half(Bb, lda, col0, N - 1, k1 + 64, ldsB + 49152 + wb, s_rowoff, s_inner);
  asm volatile("s_waitcnt vmcnt(6)" ::: "memory");
  __builtin_amdgcn_s_barrier();

  bf16x8 afP[4], afQ[4], bqP[4], bqQ[4];
#pragma unroll
  for (int m = 0; m < 4; ++m) afP[m] = ldr(ldsA, wr * 128 + m * 16 + l15, slot);
#pragma unroll
  for (int n = 0; n < 4; ++n) bqP[n] = ldr(ldsB, wc * 64 + n * 16 + l15, slot);

  for (int t = 0; t < NT; ++t) {
    const int d = t & 1;
    char* Ad = ldsA + d * 32768;
    char* Bd = ldsB + d * 32768;
    const char* Akh1 = Ad + 16384;
    const char* Bkh1 = Bd + 16384;
    const char* AkhN0 = ldsA + (d ^ 1) * 32768;
    const char* BkhN0 = ldsB + (d ^ 1) * 32768;
    const int ts1 = (t + 1 < NT) ? t + 1 : NT - 1;
    const int ts2 = (t + 2 < NT) ? t + 2 : NT - 1;

#pragma unroll
    for (int m = 0; m < 4; ++m) afQ[m] = ldr(Ad, wr * 128 + (m + 4) * 16 + l15, slot);
#pragma unroll
    for (int n = 0; n < 4; ++n) bqQ[n] = ldr(Bkh1, wc * 64 + n * 16 + l15, slot);
    stage_half(Ab, lda, row0, M - 1, ts1 * 128 + 64,
               ldsA + ((t + 1) & 1) * 32768 + 16384 + wb, s_rowoff, s_inner);
    __builtin_amdgcn_sched_barrier(0);
    __builtin_amdgcn_s_setprio(1);
#pragma unroll
    for (int m = 0; m < 4; ++m)
#pragma unroll
      for (int n = 0; n < 4; ++n)
        acc[m][n] = __builtin_amdgcn_mfma_f32_16x16x32_bf16(afP[m], bqP[n], acc[m][n], 0, 0, 0);
    __builtin_amdgcn_s_setprio(0);
    asm volatile("s_waitcnt vmcnt(8)" ::: "memory");
    __builtin_amdgcn_s_barrier();

#pragma unroll
    for (int m = 0; m < 4; ++m) afP[m] = ldr(Akh1, wr * 128 + (m + 4) * 16 + l15, slot);
    stage_half(Bb, lda, col0, N - 1, ts2 * 128, Bd + wb, s_rowoff, s_inner);
    __builtin_amdgcn_sched_barrier(0);
    __builtin_amdgcn_s_setprio(1);
#pragma unroll
    for (int m = 0; m < 4; ++m)
#pragma unroll
      for (int n = 0; n < 4; ++n)
        acc[m + 4][n] = __builtin_amdgcn_mfma_f32_16x16x32_bf16(afQ[m], bqP[n], acc[m + 4][n], 0, 0, 0);
    __builtin_amdgcn_s_setprio(0);
    __builtin_amdgcn_s_barrier();

#pragma unroll
    for (int m = 0; m < 4; ++m) afQ[m] = ldr(Akh1, wr * 128 + m * 16 + l15, slot);
    stage_half(Ab, lda, row0, M - 1, ts2 * 128, Ad + wb, s_rowoff, s_inner);
    __builtin_amdgcn_sched_barrier(0);
    __builtin_amdgcn_s_setprio(1);
#pragma unroll
    for (int m = 0; m < 4; ++m)
#pragma unroll
      for (int n = 0; n < 4; ++n)
        acc[m + 4][n] = __builtin_amdgcn_mfma_f32_16x16x32_bf16(afP[m], bqQ[n], acc[m + 4][n], 0, 0, 0);
    __builtin_amdgcn_s_setprio(0);
    asm volatile("s_waitcnt vmcnt(6)" ::: "memory");
    __builtin_amdgcn_s_barrier();

#pragma unroll
    for (int m = 0; m < 4; ++m) afP[m] = ldr(AkhN0, wr * 128 + m * 16 + l15, slot);
#pragma unroll
    for (int n = 0; n < 4; ++n) bqP[n] = ldr(BkhN0, wc * 64 + n * 16 + l15, slot);
    stage_half(Bb, lda, col0, N - 1, ts2 * 128 + 64, Bd + 16384 + wb, s_rowoff, s_inner);
    __builtin_amdgcn_sched_barrier(0);
    __builtin_amdgcn_s_setprio(1);
#pragma unroll
    for (int m = 0; m < 4; ++m)
#pragma unroll
      for (int n = 0; n < 4; ++n)
        acc[m][n] = __builtin_amdgcn_mfma_f32_16x16x32_bf16(afQ[m], bqQ[n], acc[m][n], 0, 0, 0);
    __builtin_amdgcn_s_setprio(0);
    __builtin_amdgcn_s_barrier();
  }

  float sm0 = 0.f, sm1 = 0.f;
  if (MODE == 0) {
    float w0 = wmix[0], w1 = wmix[1];
    float mx = fmaxf(w0, w1);
    float e0 = expf(w0 - mx), e1 = expf(w1 - mx);
    float inv = 1.f / (e0 + e1);
    sm0 = e0 * inv;
    sm1 = e1 * inv;
  }
  float bc[4];
  int cs[4];
#pragma unroll
  for (int n = 0; n < 4; ++n) {
    int c = col0 + wc * 64 + n * 16 + l15;
    cs[n] = c;
    bc[n] = (MODE == 2 && c >= N) ? 0.f : (bias0[c] + (MODE == 0 ? bias1[c] : 0.f));
  }
#pragma unroll
  for (int m = 0; m < 8; ++m) {
#pragma unroll
    for (int n = 0; n < 4; ++n) {
      int c = cs[n];
      if (MODE == 2 && c >= N) continue;
      int r0 = row0 + wr * 128 + m * 16 + slot * 4;
#pragma unroll
      for (int r = 0; r < 4; ++r) {
        float v = acc[m][n][r] + bc[n];
        int rr = r0 + r;
        if (MODE == 0) {
          float x1v = fmaxf(v, 0.f);
          float x2v = bf2f(x2b[(size_t)rr * DD + c]);  // pre-relu'd
          ((u16*)Cout)[(size_t)rr * ldc + c] = f2bf(sm0 * x1v + sm1 * x2v);
        } else if (MODE == 1) {
          ((u16*)Cout)[(size_t)rr * ldc + c] = f2bf(fmaxf(v, 0.f));
        } else {
          ((float*)Cout)[(size_t)rr * ldc + c] = v;
        }
      }
    }
  }
}

extern "C" void kernel_launch(void* const* d_in, const int* in_sizes, int n_in,
                              void* d_out, int out_size, void* d_ws, size_t ws_size,
                              hipStream_t stream) {
  const float* esm   = (const float*)d_in[0];
  const float* ipw   = (const float*)d_in[1];
  const float* Wesm  = (const float*)d_in[2];
  const float* besm  = (const float*)d_in[3];
  const float* bias1 = (const float*)d_in[4];
  const float* bias2 = (const float*)d_in[5];
  const float* wmix  = (const float*)d_in[6];
  const float* Wupd  = (const float*)d_in[7];
  const float* bupd  = (const float*)d_in[8];
  const float* Wout  = (const float*)d_in[9];
  const float* bout  = (const float*)d_in[10];
  const float* selfw = (const float*)d_in[11];
  const float* ppiw  = (const float*)d_in[12];
  const int* inputs  = (const int*)d_in[13];
  const int* ipidx   = (const int*)d_in[14];
  const int* ipoff   = (const int*)d_in[15];
  const int* src     = (const int*)d_in[16];
  const int* dst     = (const int*)d_in[17];
  const int* tgt     = (const int*)d_in[18];
  float* out = (float*)d_out;

  char* ws = (char*)d_ws;
  size_t o = 0;
  auto take = [&](size_t b) {
    char* r = ws + o;
    o += (b + 255) & ~(size_t)255;
    return r;
  };
  u16* Wesm_b = (u16*)take(1024ull * 1280 * 2);
  u16* Wupd_b = (u16*)take(2ull * 1024 * 2048 * 2);
  u16* Wout_b = (u16*)take(5000ull * 2304 * 2);
  int* counts  = (int*)take((size_t)NN * 4);
  int* row_off = (int*)take((size_t)(NN + 1) * 4);
  int* cursor  = (int*)take((size_t)NN * 4);
  int4* rec    = (int4*)take((size_t)EE * 16);
  u16* h_b     = (u16*)take((size_t)NN * DD * 2);
  // overlapping region (disjoint lifetimes):
  //   phase A: x2b [N,1024]bf16 @0 ; A1 [N,1280]bf16 ; ipw_b [30000,1024]bf16
  //   phase B: cat [N,2048]bf16 @0 (covers x2b+A1) ; A_last [N,2304]bf16 (covers ipw_b)
  char* shared0 = ws + o;
  size_t x2_b = ((size_t)NN * DD * 2 + 255) & ~(size_t)255;
  size_t a1_b = ((size_t)NN * DESM * 2 + 255) & ~(size_t)255;
  u16* x2b    = (u16*)shared0;
  u16* A1     = (u16*)(shared0 + x2_b);
  u16* ipw_b  = (u16*)(shared0 + x2_b + a1_b);
  u16* cat_b  = (u16*)shared0;
  u16* A_last = (u16*)(shared0 + x2_b + a1_b);

  // ---- weight casts to bf16 ----
  cast_rows_k<<<2048, 256, 0, stream>>>(Wesm, 1280, nullptr, Wesm_b, 1280, 0, 1024, 160);
  cast_rows_k<<<2048, 256, 0, stream>>>(Wupd, 2048, nullptr, Wupd_b, 2048, 0, 2048, 256);
  cast_rows_k<<<2048, 256, 0, stream>>>(Wout, 2304, nullptr, Wout_b, 2304, 0, 5000, 288);
  cast_rows_k<<<4096, 256, 0, stream>>>(ipw, 1024, nullptr, ipw_b, 1024, 0, IPN, 128);

  // ---- x2 = relu(bag + bias2) as bf16 ----
  embed_bag_k<<<NN / 2, 256, 0, stream>>>(ipw_b, ipidx, ipoff, bias2, x2b);

  // ---- gather ESM rows for x1 GEMM ----
  cast_rows_k<<<4096, 256, 0, stream>>>(esm, 1280, inputs, A1, 1280, 0, NN, 160);

  // ---- CSR by dst with packed edge records (shared by both GCN layers) ----
  hipMemsetAsync(counts, 0, (size_t)NN * 4, stream);
  hist_k<<<EE / 256, 256, 0, stream>>>(dst, counts);
  scan_k<<<1, 256, 0, stream>>>(counts, row_off);
  hipMemcpyAsync(cursor, row_off, (size_t)NN * 4, hipMemcpyDeviceToDevice, stream);
  scatter_k<<<EE / 256, 256, 0, stream>>>(dst, src, selfw, ppiw, cursor, rec);

  // ---- x1 GEMM fused with softmax-mix of x2 -> h (bf16) ----
  gemm8_k<0><<<dim3(4, 64), 512, 0, stream>>>(A1, Wesm_b, NN, 1024, 1280, h_b, 1024,
                                              besm, bias1, x2b, wmix);

  // ---- ESM gather for the final concat (A1/ipw_b dead now) ----
  cast_rows_k<<<4096, 256, 0, stream>>>(esm, 1280, tgt, A_last, 2304, 1024, NN, 160);

  // ---- GCN layer 0 ----
  aggregate_k<<<NN / 2, 256, 0, stream>>>(h_b, row_off, rec, cat_b);
  gemm8_k<1><<<dim3(4, 64), 512, 0, stream>>>(cat_b, Wupd_b, NN, 1024, 2048, h_b, 1024,
                                              bupd, nullptr, nullptr, nullptr);

  // ---- GCN layer 1 (writes h directly into A_last[:, :1024]) ----
  aggregate_k<<<NN / 2, 256, 0, stream>>>(h_b, row_off, rec, cat_b);
  gemm8_k<1><<<dim3(4, 64), 512, 0, stream>>>(cat_b, Wupd_b + (size_t)1024 * 2048, NN, 1024,
                                              2048, A_last, 2304, bupd + 1024, nullptr,
                                              nullptr, nullptr);

  // ---- final output GEMM [16384,2304] x [5000,2304]^T ----
  gemm8_k<2><<<dim3(20, 64), 512, 0, stream>>>(A_last, Wout_b, NN, 5000, 2304, out, 5000,
                                               bout, nullptr, nullptr, nullptr);
}